// Round 2
// baseline (780.064 us; speedup 1.0000x reference)
//
#include <hip/hip_runtime.h>

// Problem: Bahdanau additive attention. S=2048, B=32, H=1024.
// context[b,h] = sum_s softmax_s(mask(v . tanh(W1 hs + b1 + W2 h + b2))) * hs
//
// Pipeline (all on `stream`):
//  1) t2[b,n]   = b1[n] + b2[n] + sum_h hidden[b,h]*W2[n,h]        (fp32, small)
//  2) epart[nb][m] = sum_{n in slice nb} tanh(hs@W1^T + t2)*v[n]   (f16 MFMA GEMM, fused epilogue)
//  3) energy[m] = sum_nb epart; masked softmax over s per b -> attn
//  4) ctxp[sc][b][h] = partial sum_s attn*hs                        (skip attn==0)
//  5) out[b][h] = sum_sc ctxp
//
// NOTE input order is the setup_inputs() dict order:
//   d_in[0]=hidden d_in[1]=hidden_sequence d_in[2]=input_masks
//   d_in[3]=W1 d_in[4]=b1 d_in[5]=W2 d_in[6]=b2 d_in[7]=v
// (round-1 crash was d_in[5]/d_in[6] swapped -> b2 buffer indexed as HxH matrix)

#define SS 2048
#define BB 32
#define HH 1024
#define MM (SS*BB)   // 65536

typedef _Float16 f16;
typedef __attribute__((ext_vector_type(8))) _Float16 f16x8;
typedef __attribute__((ext_vector_type(4))) _Float16 f16x4;
typedef __attribute__((ext_vector_type(4))) float   floatx4;

__device__ __forceinline__ float tanh_fast(float x) {
  // 1 - 2/(exp(2x)+1); exact limits at +/-inf, ~1e-6 abs err
  float e = __expf(2.0f * x);
  return 1.0f - 2.0f / (e + 1.0f);
}

// ---------------- kernel 1: t2 = hidden @ W2^T + b1 + b2 ----------------
// one wave per (b,n) dot product of length 1024
__global__ __launch_bounds__(256) void t2_kernel(
    const float* __restrict__ hidden, const float* __restrict__ W2,
    const float* __restrict__ b1, const float* __restrict__ b2,
    float* __restrict__ t2)
{
  const int gw   = blockIdx.x * 4 + (threadIdx.x >> 6); // 0..32767
  const int b    = gw >> 10;
  const int n    = gw & 1023;
  const int lane = threadIdx.x & 63;
  float acc = 0.f;
#pragma unroll
  for (int q = 0; q < 4; ++q) {
    floatx4 hv = *(const floatx4*)&hidden[b * HH + q * 256 + lane * 4];
    floatx4 wv = *(const floatx4*)&W2[(size_t)n * HH + q * 256 + lane * 4];
    acc += hv.x * wv.x + hv.y * wv.y + hv.z * wv.z + hv.w * wv.w;
  }
#pragma unroll
  for (int off = 1; off < 64; off <<= 1) acc += __shfl_xor(acc, off);
  if (lane == 0) t2[b * HH + n] = acc + b1[n] + b2[n];
}

// ---------------- kernel 2: fused GEMM + tanh + dot(v) ----------------
// C[m,n] = sum_k hs[m,k]*W1[n,k]  (both row-major in k -> B^T layout GEMM)
// block tile 128(M) x 128(N), BK=64, 4 waves each 32(M)x128(N)
// epilogue: epart[nb*MM + m] = sum_{n in tile} tanh(C+t2[b,n])*v[n]
__global__ __launch_bounds__(256) void gemm_energy(
    const float* __restrict__ hs, const float* __restrict__ W1,
    const float* __restrict__ t2, const float* __restrict__ v,
    float* __restrict__ epart)
{
  const int tid = threadIdx.x;
  const int nb  = blockIdx.x;        // 0..7  (N-major grid: A-tile sharers adjacent)
  const int mB  = blockIdx.y * 128;  // 0..511 tiles

  __shared__ __align__(16) f16 Asm[128][72]; // +8 pad: 2-way LDS aliasing only
  __shared__ __align__(16) f16 Bsm[128][72];

  const int lane = tid & 63;
  const int w    = tid >> 6;   // wave 0..3 -> rows w*32..w*32+31
  const int quad = lane >> 4;
  const int l15  = lane & 15;

  floatx4 acc[2][8];
#pragma unroll
  for (int i = 0; i < 2; ++i)
#pragma unroll
    for (int j = 0; j < 8; ++j) acc[i][j] = (floatx4){0.f, 0.f, 0.f, 0.f};

  const int srow = tid >> 4;        // staging: 16 threads/row, 16 rows/pass
  const int scol = (tid & 15) * 4;

  const float* Abase = hs + (size_t)(mB + srow) * HH + scol;
  const float* Bbase = W1 + (size_t)(nb * 128 + srow) * HH + scol;

  for (int kt = 0; kt < HH; kt += 64) {
#pragma unroll
    for (int p = 0; p < 8; ++p) {
      floatx4 fa = *(const floatx4*)(Abase + (size_t)(p * 16) * HH + kt);
      floatx4 fb = *(const floatx4*)(Bbase + (size_t)(p * 16) * HH + kt);
      f16x4 ha = {(f16)fa.x, (f16)fa.y, (f16)fa.z, (f16)fa.w};
      f16x4 hb = {(f16)fb.x, (f16)fb.y, (f16)fb.z, (f16)fb.w};
      *(f16x4*)&Asm[p * 16 + srow][scol] = ha;
      *(f16x4*)&Bsm[p * 16 + srow][scol] = hb;
    }
    __syncthreads();
#pragma unroll
    for (int ks = 0; ks < 2; ++ks) {
      f16x8 af[2], bfr[8];
#pragma unroll
      for (int i = 0; i < 2; ++i)
        af[i] = *(const f16x8*)&Asm[w * 32 + i * 16 + l15][ks * 32 + quad * 8];
#pragma unroll
      for (int j = 0; j < 8; ++j)
        bfr[j] = *(const f16x8*)&Bsm[j * 16 + l15][ks * 32 + quad * 8];
#pragma unroll
      for (int i = 0; i < 2; ++i)
#pragma unroll
        for (int j = 0; j < 8; ++j)
          acc[i][j] = __builtin_amdgcn_mfma_f32_16x16x32_f16(af[i], bfr[j], acc[i][j], 0, 0, 0);
    }
    __syncthreads();
  }

  // epilogue: C/D layout col=lane&15, row=quad*4+reg (m89-verified)
  const int nB = nb * 128;
#pragma unroll
  for (int i = 0; i < 2; ++i) {
#pragma unroll
    for (int reg = 0; reg < 4; ++reg) {
      const int m = mB + w * 32 + i * 16 + quad * 4 + reg;
      const int b = m & (BB - 1);
      float rs = 0.f;
#pragma unroll
      for (int j = 0; j < 8; ++j) {
        const int n = nB + j * 16 + l15;
        const float val = acc[i][j][reg] + t2[b * HH + n];
        rs += tanh_fast(val) * v[n];
      }
      rs += __shfl_xor(rs, 1);
      rs += __shfl_xor(rs, 2);
      rs += __shfl_xor(rs, 4);
      rs += __shfl_xor(rs, 8);
      if (l15 == 0) epart[(size_t)nb * MM + m] = rs;
    }
  }
}

// ---------------- kernel 3: masked softmax over s, per batch column ----------------
__global__ __launch_bounds__(256) void softmax_kernel(
    const float* __restrict__ epart, const int* __restrict__ masks,
    float* __restrict__ attn)
{
  const int b = blockIdx.x;
  const int tid = threadIdx.x;
  __shared__ float redm[4], reds[4];
  float em[8];
  float lmax = -3e38f;
#pragma unroll
  for (int it = 0; it < 8; ++it) {
    const int s = it * 256 + tid;
    float e = 0.f;
#pragma unroll
    for (int p = 0; p < 8; ++p) e += epart[(size_t)p * MM + s * BB + b];
    if (masks[s * BB + b] == 0) e = -1e10f;
    em[it] = e;
    lmax = fmaxf(lmax, e);
  }
#pragma unroll
  for (int off = 1; off < 64; off <<= 1) lmax = fmaxf(lmax, __shfl_xor(lmax, off));
  if ((tid & 63) == 0) redm[tid >> 6] = lmax;
  __syncthreads();
  lmax = fmaxf(fmaxf(redm[0], redm[1]), fmaxf(redm[2], redm[3]));
  float lsum = 0.f;
#pragma unroll
  for (int it = 0; it < 8; ++it) { em[it] = __expf(em[it] - lmax); lsum += em[it]; }
#pragma unroll
  for (int off = 1; off < 64; off <<= 1) lsum += __shfl_xor(lsum, off);
  if ((tid & 63) == 0) reds[tid >> 6] = lsum;
  __syncthreads();
  const float inv = 1.0f / (reds[0] + reds[1] + reds[2] + reds[3]);
#pragma unroll
  for (int it = 0; it < 8; ++it) attn[(it * 256 + tid) * BB + b] = em[it] * inv;
}

// ---------------- kernel 4: context partials ----------------
__global__ __launch_bounds__(256) void context_part(
    const float* __restrict__ hs, const float* __restrict__ attn,
    float* __restrict__ ctxp)
{
  const int b  = blockIdx.x;
  const int sc = blockIdx.y;
  const int tid = threadIdx.x;
  floatx4 acc = {0.f, 0.f, 0.f, 0.f};
  for (int s = sc * 256; s < sc * 256 + 256; ++s) {
    const float a = attn[s * BB + b];
    if (a != 0.f) {  // masked rows have attn exactly 0 -> skip ~half the reads
      floatx4 h = *(const floatx4*)&hs[(size_t)(s * BB + b) * HH + tid * 4];
      acc.x += a * h.x; acc.y += a * h.y; acc.z += a * h.z; acc.w += a * h.w;
    }
  }
  *(floatx4*)&ctxp[(size_t)(sc * BB + b) * HH + tid * 4] = acc;
}

// ---------------- kernel 5: reduce 8 context partials ----------------
__global__ __launch_bounds__(256) void ctx_reduce(
    const float* __restrict__ ctxp, float* __restrict__ out)
{
  const int i = blockIdx.x * 256 + threadIdx.x;
  float s = 0.f;
#pragma unroll
  for (int sc = 0; sc < 8; ++sc) s += ctxp[(size_t)sc * (BB * HH) + i];
  out[i] = s;
}

extern "C" void kernel_launch(void* const* d_in, const int* in_sizes, int n_in,
                              void* d_out, int out_size, void* d_ws, size_t ws_size,
                              hipStream_t stream) {
  const float* hidden = (const float*)d_in[0];  // (1,B,H)    32768
  const float* hs     = (const float*)d_in[1];  // (S,B,H)    67108864
  const int*   masks  = (const int*)d_in[2];    // (S,B)      65536
  const float* W1     = (const float*)d_in[3];  // (H,H)      1048576
  const float* b1     = (const float*)d_in[4];  // (H,)       1024
  const float* W2     = (const float*)d_in[5];  // (H,H)      1048576
  const float* b2     = (const float*)d_in[6];  // (H,)       1024
  const float* v      = (const float*)d_in[7];  // (H,)       1024
  float* out = (float*)d_out;                   // (1,B,H)

  // workspace layout (floats): total ~3.4 MB
  float* epart = (float*)d_ws;          // 8*MM   = 524288
  float* attn  = epart + 8 * MM;        // MM     = 65536
  float* t2    = attn + MM;             // BB*HH  = 32768
  float* ctxp  = t2 + BB * HH;          // 8*BB*HH= 262144

  t2_kernel<<<dim3(BB * HH / 4), 256, 0, stream>>>(hidden, W2, b1, b2, t2);
  gemm_energy<<<dim3(8, MM / 128), 256, 0, stream>>>(hs, W1, t2, v, epart);
  softmax_kernel<<<dim3(BB), 256, 0, stream>>>(epart, masks, attn);
  context_part<<<dim3(BB, 8), 256, 0, stream>>>(hs, attn, ctxp);
  ctx_reduce<<<dim3(BB * HH / 256), 256, 0, stream>>>(ctxp, out);
}

// Round 4
// 710.213 us; speedup vs baseline: 1.0984x; 1.0984x over previous
//
#include <hip/hip_runtime.h>
#include <stdint.h>

// Bahdanau additive attention. S=2048, B=32, H=1024.
// context[b,h] = sum_s softmax_s(mask(v . tanh(W1 hs + b1 + W2 h + b2))) * hs
//
// Fast path (needs ~138.4 MB workspace):
//  0) convert_f16: hs,W1 -> f16 copies in ws (memory-bound, ~61 us)
//  1) t2_kernel:   t2[b,n] = b1[n]+b2[n]+hidden.W2row  (W2 rows read once)
//  2) gemm_energy_f16: 128x128x(BK=64) f16 MFMA, global_load_lds(16B) staging,
//     XOR-swizzled LDS (conflict-free b128 reads), XCD-aware block swizzle,
//     fused tanh+dot(v) epilogue -> 16 partial-energy slices
//  3) softmax16: reduce 16 slices, mask, softmax over s per b
//  4) context_f16: ctxp[sc] partial sums. 256 thr x f16x4 = H=1024 exactly.
//     (round-3 FAIL: f16x8 with 256 thr spanned 2048 -> OOB write race in ctxp)
//  5) ctx_reduce32
// Fallback path = round-2 kernels (3.4 MB ws), known-passing.

#define SS 2048
#define BB 32
#define HH 1024
#define MM (SS*BB)   // 65536

typedef _Float16 f16;
typedef __attribute__((ext_vector_type(8))) _Float16 f16x8;
typedef __attribute__((ext_vector_type(4))) _Float16 f16x4;
typedef __attribute__((ext_vector_type(4))) float   floatx4;

__device__ __forceinline__ float tanh_fast(float x) {
  float e = __expf(2.0f * x);
  return 1.0f - 2.0f / (e + 1.0f);
}

// async global->LDS, 16B/lane. LDS dest = wave-uniform base + lane*16.
// AS casts go through integers: flat LDS addresses carry the LDS offset in
// the low 32 bits (aperture in high bits), so truncation = addrspacecast.
__device__ __forceinline__ void gload16(void* lds_base, const void* gptr) {
  __builtin_amdgcn_global_load_lds(
      (const __attribute__((address_space(1))) uint32_t*)(uintptr_t)gptr,
      (__attribute__((address_space(3))) uint32_t*)(uint32_t)(uintptr_t)lds_base,
      16, 0, 0);
}

// ---------------- convert: fp32 -> f16 for hs and W1 ----------------
__global__ __launch_bounds__(256) void convert_f16(
    const float* __restrict__ hs, const float* __restrict__ W1,
    f16* __restrict__ hsf, f16* __restrict__ W1f)
{
  const size_t NH = (size_t)MM * HH;   // 64M
  size_t base = ((size_t)blockIdx.x * 256 + threadIdx.x) * 8;
  if (base < NH) {
    floatx4 a = *(const floatx4*)&hs[base];
    floatx4 b = *(const floatx4*)&hs[base + 4];
    f16x8 o = {(f16)a.x,(f16)a.y,(f16)a.z,(f16)a.w,(f16)b.x,(f16)b.y,(f16)b.z,(f16)b.w};
    *(f16x8*)&hsf[base] = o;
  } else {
    size_t wb = base - NH;
    if (wb < (size_t)HH * HH) {
      floatx4 a = *(const floatx4*)&W1[wb];
      floatx4 b = *(const floatx4*)&W1[wb + 4];
      f16x8 o = {(f16)a.x,(f16)a.y,(f16)a.z,(f16)a.w,(f16)b.x,(f16)b.y,(f16)b.z,(f16)b.w};
      *(f16x8*)&W1f[wb] = o;
    }
  }
}

// ---------------- t2 = hidden @ W2^T + b1 + b2 ----------------
// b fastest -> consecutive waves share the W2 row (read once from HBM)
__global__ __launch_bounds__(256) void t2_kernel(
    const float* __restrict__ hidden, const float* __restrict__ W2,
    const float* __restrict__ b1, const float* __restrict__ b2,
    float* __restrict__ t2)
{
  const int gw   = blockIdx.x * 4 + (threadIdx.x >> 6);
  const int n    = gw >> 5;
  const int b    = gw & 31;
  const int lane = threadIdx.x & 63;
  float acc = 0.f;
#pragma unroll
  for (int q = 0; q < 4; ++q) {
    floatx4 hv = *(const floatx4*)&hidden[b * HH + q * 256 + lane * 4];
    floatx4 wv = *(const floatx4*)&W2[(size_t)n * HH + q * 256 + lane * 4];
    acc += hv.x * wv.x + hv.y * wv.y + hv.z * wv.z + hv.w * wv.w;
  }
#pragma unroll
  for (int off = 1; off < 64; off <<= 1) acc += __shfl_xor(acc, off);
  if (lane == 0) t2[b * HH + n] = acc + b1[n] + b2[n];
}

// ---------------- f16 MFMA GEMM + tanh + dot(v) ----------------
// C[m,n] = sum_k hsf[m,k]*W1f[n,k]; 128x128 tile, BK=64, 4 waves 2x2,
// each wave 64x64 = 4x4 frags of 16x16x32. LDS layout: slot(r,cb_phys),
// cb_phys = cb_logical ^ (r&7) -> b128 frag reads are 2-way (free).
__global__ __launch_bounds__(256) void gemm_energy_f16(
    const f16* __restrict__ hsf, const f16* __restrict__ W1f,
    const float* __restrict__ t2, const float* __restrict__ v,
    float* __restrict__ epart)
{
  __shared__ __align__(16) f16 Asm[128 * 64];
  __shared__ __align__(16) f16 Bsm[128 * 64];

  const int tid  = threadIdx.x;
  const int lane = tid & 63;
  const int w    = tid >> 6;
  const int quad = lane >> 4;
  const int l15  = lane & 15;
  const int wr   = w >> 1, wc = w & 1;

  // XCD-aware swizzle: 8 nb-blocks of one m-tile land consecutively on one XCD
  const int l     = blockIdx.x;
  const int x     = l & 7;
  const int jj_   = l >> 3;
  const int nb    = jj_ & 7;
  const int mtile = (jj_ >> 3) * 8 + x;
  const int mB    = mtile * 128;
  const int nB    = nb * 128;

  floatx4 acc[4][4];
#pragma unroll
  for (int i = 0; i < 4; ++i)
#pragma unroll
    for (int j = 0; j < 4; ++j) acc[i][j] = (floatx4){0.f, 0.f, 0.f, 0.f};

  for (int kt = 0; kt < HH; kt += 64) {
#pragma unroll
    for (int q = 0; q < 4; ++q) {
      const int W   = w * 4 + q;                 // wave-instruction index 0..15
      const int r   = W * 8 + (lane >> 3);       // tile row this lane fetches
      const int cbl = (lane & 7) ^ (r & 7);      // logical 16B colblock (XOR swizzle)
      gload16(&Asm[W * 64 * 8], &hsf[(size_t)(mB + r) * HH + kt + cbl * 8]);
      gload16(&Bsm[W * 64 * 8], &W1f[(size_t)(nB + r) * HH + kt + cbl * 8]);
    }
    __syncthreads();   // compiler drains vmcnt before s_barrier
#pragma unroll
    for (int ks = 0; ks < 2; ++ks) {
      f16x8 af[4], bfr[4];
#pragma unroll
      for (int i = 0; i < 4; ++i) {
        const int r   = wr * 64 + i * 16 + l15;
        const int cbp = (ks * 4 + quad) ^ (r & 7);
        af[i] = *(const f16x8*)&Asm[(r * 8 + cbp) * 8];
      }
#pragma unroll
      for (int j = 0; j < 4; ++j) {
        const int r   = wc * 64 + j * 16 + l15;
        const int cbp = (ks * 4 + quad) ^ (r & 7);
        bfr[j] = *(const f16x8*)&Bsm[(r * 8 + cbp) * 8];
      }
#pragma unroll
      for (int i = 0; i < 4; ++i)
#pragma unroll
        for (int j = 0; j < 4; ++j)
          acc[i][j] = __builtin_amdgcn_mfma_f32_16x16x32_f16(af[i], bfr[j], acc[i][j], 0, 0, 0);
    }
    __syncthreads();
  }

  // epilogue: C/D layout col=lane&15, row=quad*4+reg (verified round 2)
  float vv[4];
#pragma unroll
  for (int j = 0; j < 4; ++j) vv[j] = v[nB + wc * 64 + j * 16 + l15];
#pragma unroll
  for (int i = 0; i < 4; ++i) {
#pragma unroll
    for (int reg = 0; reg < 4; ++reg) {
      const int m = mB + wr * 64 + i * 16 + quad * 4 + reg;
      const int b = m & (BB - 1);
      float rs = 0.f;
#pragma unroll
      for (int j = 0; j < 4; ++j) {
        const int n = nB + wc * 64 + j * 16 + l15;
        rs += tanh_fast(acc[i][j][reg] + t2[b * HH + n]) * vv[j];
      }
      rs += __shfl_xor(rs, 1);
      rs += __shfl_xor(rs, 2);
      rs += __shfl_xor(rs, 4);
      rs += __shfl_xor(rs, 8);
      if (l15 == 0) epart[(size_t)(nb * 2 + wc) * MM + m] = rs;
    }
  }
}

// ---------------- softmax over s per batch column (16 partials) ----------------
__global__ __launch_bounds__(256) void softmax16(
    const float* __restrict__ epart, const int* __restrict__ masks,
    float* __restrict__ attn)
{
  const int b = blockIdx.x;
  const int tid = threadIdx.x;
  __shared__ float redm[4], reds[4];
  float em[8];
  float lmax = -3e38f;
#pragma unroll
  for (int it = 0; it < 8; ++it) {
    const int s = it * 256 + tid;
    float e = 0.f;
#pragma unroll
    for (int p = 0; p < 16; ++p) e += epart[(size_t)p * MM + s * BB + b];
    if (masks[s * BB + b] == 0) e = -1e10f;
    em[it] = e;
    lmax = fmaxf(lmax, e);
  }
#pragma unroll
  for (int off = 1; off < 64; off <<= 1) lmax = fmaxf(lmax, __shfl_xor(lmax, off));
  if ((tid & 63) == 0) redm[tid >> 6] = lmax;
  __syncthreads();
  lmax = fmaxf(fmaxf(redm[0], redm[1]), fmaxf(redm[2], redm[3]));
  float lsum = 0.f;
#pragma unroll
  for (int it = 0; it < 8; ++it) { em[it] = __expf(em[it] - lmax); lsum += em[it]; }
#pragma unroll
  for (int off = 1; off < 64; off <<= 1) lsum += __shfl_xor(lsum, off);
  if ((tid & 63) == 0) reds[tid >> 6] = lsum;
  __syncthreads();
  const float inv = 1.0f / (reds[0] + reds[1] + reds[2] + reds[3]);
#pragma unroll
  for (int it = 0; it < 8; ++it) attn[(it * 256 + tid) * BB + b] = em[it] * inv;
}

// ---------------- context partials from f16 hs ----------------
// 256 threads x f16x4 = exactly H=1024 elements per row. (Do NOT widen to
// f16x8 without halving thread H-coverage: that was the round-3 OOB bug.)
__global__ __launch_bounds__(256) void context_f16(
    const f16* __restrict__ hsf, const float* __restrict__ attn,
    float* __restrict__ ctxp)
{
  const int b  = blockIdx.x;
  const int sc = blockIdx.y;    // 32 chunks of 64 s
  const int tid = threadIdx.x;  // tid*4 covers H=1024
  floatx4 acc = {0.f, 0.f, 0.f, 0.f};
  for (int s = sc * 64; s < sc * 64 + 64; ++s) {
    const float a = attn[s * BB + b];
    if (a != 0.f) {
      f16x4 h = *(const f16x4*)&hsf[(size_t)(s * BB + b) * HH + tid * 4];
      acc.x += a * (float)h[0];
      acc.y += a * (float)h[1];
      acc.z += a * (float)h[2];
      acc.w += a * (float)h[3];
    }
  }
  *(floatx4*)&ctxp[(size_t)(sc * BB + b) * HH + tid * 4] = acc;
}

__global__ __launch_bounds__(256) void ctx_reduce32(
    const float* __restrict__ ctxp, float* __restrict__ out)
{
  const int i = blockIdx.x * 256 + threadIdx.x;
  float s = 0.f;
#pragma unroll
  for (int sc = 0; sc < 32; ++sc) s += ctxp[(size_t)sc * (BB * HH) + i];
  out[i] = s;
}

// ================= fallback path (round-2, known-passing, 3.4 MB ws) =================
__global__ __launch_bounds__(256) void gemm_energy_fb(
    const float* __restrict__ hs, const float* __restrict__ W1,
    const float* __restrict__ t2, const float* __restrict__ v,
    float* __restrict__ epart)
{
  const int tid = threadIdx.x;
  const int nb  = blockIdx.x;
  const int mB  = blockIdx.y * 128;
  __shared__ __align__(16) f16 Asm[128][72];
  __shared__ __align__(16) f16 Bsm[128][72];
  const int lane = tid & 63;
  const int w    = tid >> 6;
  const int quad = lane >> 4;
  const int l15  = lane & 15;
  floatx4 acc[2][8];
#pragma unroll
  for (int i = 0; i < 2; ++i)
#pragma unroll
    for (int j = 0; j < 8; ++j) acc[i][j] = (floatx4){0.f, 0.f, 0.f, 0.f};
  const int srow = tid >> 4;
  const int scol = (tid & 15) * 4;
  const float* Abase = hs + (size_t)(mB + srow) * HH + scol;
  const float* Bbase = W1 + (size_t)(nb * 128 + srow) * HH + scol;
  for (int kt = 0; kt < HH; kt += 64) {
#pragma unroll
    for (int p = 0; p < 8; ++p) {
      floatx4 fa = *(const floatx4*)(Abase + (size_t)(p * 16) * HH + kt);
      floatx4 fb = *(const floatx4*)(Bbase + (size_t)(p * 16) * HH + kt);
      f16x4 ha = {(f16)fa.x, (f16)fa.y, (f16)fa.z, (f16)fa.w};
      f16x4 hb = {(f16)fb.x, (f16)fb.y, (f16)fb.z, (f16)fb.w};
      *(f16x4*)&Asm[p * 16 + srow][scol] = ha;
      *(f16x4*)&Bsm[p * 16 + srow][scol] = hb;
    }
    __syncthreads();
#pragma unroll
    for (int ks = 0; ks < 2; ++ks) {
      f16x8 af[2], bfr[8];
#pragma unroll
      for (int i = 0; i < 2; ++i)
        af[i] = *(const f16x8*)&Asm[w * 32 + i * 16 + l15][ks * 32 + quad * 8];
#pragma unroll
      for (int j = 0; j < 8; ++j)
        bfr[j] = *(const f16x8*)&Bsm[j * 16 + l15][ks * 32 + quad * 8];
#pragma unroll
      for (int i = 0; i < 2; ++i)
#pragma unroll
        for (int j = 0; j < 8; ++j)
          acc[i][j] = __builtin_amdgcn_mfma_f32_16x16x32_f16(af[i], bfr[j], acc[i][j], 0, 0, 0);
    }
    __syncthreads();
  }
  const int nB = nb * 128;
#pragma unroll
  for (int i = 0; i < 2; ++i) {
#pragma unroll
    for (int reg = 0; reg < 4; ++reg) {
      const int m = mB + w * 32 + i * 16 + quad * 4 + reg;
      const int b = m & (BB - 1);
      float rs = 0.f;
#pragma unroll
      for (int j = 0; j < 8; ++j) {
        const int n = nB + j * 16 + l15;
        rs += tanh_fast(acc[i][j][reg] + t2[b * HH + n]) * v[n];
      }
      rs += __shfl_xor(rs, 1);
      rs += __shfl_xor(rs, 2);
      rs += __shfl_xor(rs, 4);
      rs += __shfl_xor(rs, 8);
      if (l15 == 0) epart[(size_t)nb * MM + m] = rs;
    }
  }
}

__global__ __launch_bounds__(256) void softmax8(
    const float* __restrict__ epart, const int* __restrict__ masks,
    float* __restrict__ attn)
{
  const int b = blockIdx.x;
  const int tid = threadIdx.x;
  __shared__ float redm[4], reds[4];
  float em[8];
  float lmax = -3e38f;
#pragma unroll
  for (int it = 0; it < 8; ++it) {
    const int s = it * 256 + tid;
    float e = 0.f;
#pragma unroll
    for (int p = 0; p < 8; ++p) e += epart[(size_t)p * MM + s * BB + b];
    if (masks[s * BB + b] == 0) e = -1e10f;
    em[it] = e;
    lmax = fmaxf(lmax, e);
  }
#pragma unroll
  for (int off = 1; off < 64; off <<= 1) lmax = fmaxf(lmax, __shfl_xor(lmax, off));
  if ((tid & 63) == 0) redm[tid >> 6] = lmax;
  __syncthreads();
  lmax = fmaxf(fmaxf(redm[0], redm[1]), fmaxf(redm[2], redm[3]));
  float lsum = 0.f;
#pragma unroll
  for (int it = 0; it < 8; ++it) { em[it] = __expf(em[it] - lmax); lsum += em[it]; }
#pragma unroll
  for (int off = 1; off < 64; off <<= 1) lsum += __shfl_xor(lsum, off);
  if ((tid & 63) == 0) reds[tid >> 6] = lsum;
  __syncthreads();
  const float inv = 1.0f / (reds[0] + reds[1] + reds[2] + reds[3]);
#pragma unroll
  for (int it = 0; it < 8; ++it) attn[(it * 256 + tid) * BB + b] = em[it] * inv;
}

__global__ __launch_bounds__(256) void context_fb(
    const float* __restrict__ hs, const float* __restrict__ attn,
    float* __restrict__ ctxp)
{
  const int b  = blockIdx.x;
  const int sc = blockIdx.y;
  const int tid = threadIdx.x;
  floatx4 acc = {0.f, 0.f, 0.f, 0.f};
  for (int s = sc * 256; s < sc * 256 + 256; ++s) {
    const float a = attn[s * BB + b];
    if (a != 0.f) {
      floatx4 h = *(const floatx4*)&hs[(size_t)(s * BB + b) * HH + tid * 4];
      acc.x += a * h.x; acc.y += a * h.y; acc.z += a * h.z; acc.w += a * h.w;
    }
  }
  *(floatx4*)&ctxp[(size_t)(sc * BB + b) * HH + tid * 4] = acc;
}

__global__ __launch_bounds__(256) void ctx_reduce8(
    const float* __restrict__ ctxp, float* __restrict__ out)
{
  const int i = blockIdx.x * 256 + threadIdx.x;
  float s = 0.f;
#pragma unroll
  for (int sc = 0; sc < 8; ++sc) s += ctxp[(size_t)sc * (BB * HH) + i];
  out[i] = s;
}

extern "C" void kernel_launch(void* const* d_in, const int* in_sizes, int n_in,
                              void* d_out, int out_size, void* d_ws, size_t ws_size,
                              hipStream_t stream) {
  const float* hidden = (const float*)d_in[0];  // (1,B,H)
  const float* hs     = (const float*)d_in[1];  // (S,B,H)
  const int*   masks  = (const int*)d_in[2];    // (S,B)
  const float* W1     = (const float*)d_in[3];  // (H,H)
  const float* b1     = (const float*)d_in[4];  // (H,)
  const float* W2     = (const float*)d_in[5];  // (H,H)
  const float* b2     = (const float*)d_in[6];  // (H,)
  const float* v      = (const float*)d_in[7];  // (H,)
  float* out = (float*)d_out;                   // (1,B,H)

  const size_t hsf_b   = (size_t)MM * HH * 2;    // 128 MB
  const size_t w1f_b   = (size_t)HH * HH * 2;    // 2 MB
  const size_t epart_b = (size_t)16 * MM * 4;    // 4 MB
  const size_t attn_b  = (size_t)MM * 4;         // 256 KB
  const size_t t2_b    = (size_t)BB * HH * 4;    // 128 KB
  const size_t ctxp_b  = (size_t)32 * BB * HH * 4; // 4 MB
  const size_t need = hsf_b + w1f_b + epart_b + attn_b + t2_b + ctxp_b;

  if (ws_size >= need) {
    char* p = (char*)d_ws;
    f16*   hsf   = (f16*)p;              p += hsf_b;
    f16*   W1f   = (f16*)p;              p += w1f_b;
    float* epart = (float*)p;            p += epart_b;
    float* attn  = (float*)p;            p += attn_b;
    float* t2    = (float*)p;            p += t2_b;
    float* ctxp  = (float*)p;

    convert_f16<<<dim3(33280), 256, 0, stream>>>(hs, W1, hsf, W1f);
    t2_kernel<<<dim3(BB * HH / 4), 256, 0, stream>>>(hidden, W2, b1, b2, t2);
    gemm_energy_f16<<<dim3(4096), 256, 0, stream>>>(hsf, W1f, t2, v, epart);
    softmax16<<<dim3(BB), 256, 0, stream>>>(epart, masks, attn);
    context_f16<<<dim3(BB, 32), 256, 0, stream>>>(hsf, attn, ctxp);
    ctx_reduce32<<<dim3(BB * HH / 256), 256, 0, stream>>>(ctxp, out);
  } else {
    float* epart = (float*)d_ws;          // 8*MM
    float* attn  = epart + 8 * MM;        // MM
    float* t2    = attn + MM;             // BB*HH
    float* ctxp  = t2 + BB * HH;          // 8*BB*HH

    t2_kernel<<<dim3(BB * HH / 4), 256, 0, stream>>>(hidden, W2, b1, b2, t2);
    gemm_energy_fb<<<dim3(8, MM / 128), 256, 0, stream>>>(hs, W1, t2, v, epart);
    softmax8<<<dim3(BB), 256, 0, stream>>>(epart, masks, attn);
    context_fb<<<dim3(BB, 8), 256, 0, stream>>>(hs, attn, ctxp);
    ctx_reduce8<<<dim3(BB * HH / 256), 256, 0, stream>>>(ctxp, out);
  }
}

// Round 5
// 650.109 us; speedup vs baseline: 1.1999x; 1.0925x over previous
//
#include <hip/hip_runtime.h>
#include <stdint.h>

// Bahdanau additive attention. S=2048, B=32, H=1024.
// context[b,h] = sum_s softmax_s(mask(v . tanh(W1 hs + b1 + W2 h + b2))) * hs
//
// Fast path (needs ~138.4 MB workspace):
//  0) convert_f16: hs,W1 -> f16 copies in ws
//  1) t2_kernel:   t2[b,n] = b1[n]+b2[n]+hidden.W2row
//  2) gemm_energy_f16: 128x128x(BK=64) f16 MFMA, global_load_lds(16B),
//     XOR-swizzled LDS (0 bank conflicts, verified r4), XCD-aware swizzle
//     (FETCH 1.07GB->90MB, verified r4), fused tanh+dot(v) epilogue.
//     Round-5: epilogue writes epart[p][b][s] (transposed) for coalesced softmax.
//  3) softmax16t: 32 blocks x 1024 thr, coalesced slice reduction, attn[b][s]
//  4) context_f16t: attn chunk preloaded to LDS, unrolled hs row loads
//  5) ctx_reduce32
// Fallback path = round-2 kernels (3.4 MB ws), known-passing, own layouts.

#define SS 2048
#define BB 32
#define HH 1024
#define MM (SS*BB)   // 65536

typedef _Float16 f16;
typedef __attribute__((ext_vector_type(8))) _Float16 f16x8;
typedef __attribute__((ext_vector_type(4))) _Float16 f16x4;
typedef __attribute__((ext_vector_type(4))) float   floatx4;

__device__ __forceinline__ float tanh_fast(float x) {
  float e = __expf(2.0f * x);
  return 1.0f - 2.0f / (e + 1.0f);
}

// async global->LDS, 16B/lane. LDS dest = wave-uniform base + lane*16.
__device__ __forceinline__ void gload16(void* lds_base, const void* gptr) {
  __builtin_amdgcn_global_load_lds(
      (const __attribute__((address_space(1))) uint32_t*)(uintptr_t)gptr,
      (__attribute__((address_space(3))) uint32_t*)(uint32_t)(uintptr_t)lds_base,
      16, 0, 0);
}

// ---------------- convert: fp32 -> f16 for hs and W1 ----------------
__global__ __launch_bounds__(256) void convert_f16(
    const float* __restrict__ hs, const float* __restrict__ W1,
    f16* __restrict__ hsf, f16* __restrict__ W1f)
{
  const size_t NH = (size_t)MM * HH;   // 64M
  size_t base = ((size_t)blockIdx.x * 256 + threadIdx.x) * 8;
  if (base < NH) {
    floatx4 a = *(const floatx4*)&hs[base];
    floatx4 b = *(const floatx4*)&hs[base + 4];
    f16x8 o = {(f16)a.x,(f16)a.y,(f16)a.z,(f16)a.w,(f16)b.x,(f16)b.y,(f16)b.z,(f16)b.w};
    *(f16x8*)&hsf[base] = o;
  } else {
    size_t wb = base - NH;
    if (wb < (size_t)HH * HH) {
      floatx4 a = *(const floatx4*)&W1[wb];
      floatx4 b = *(const floatx4*)&W1[wb + 4];
      f16x8 o = {(f16)a.x,(f16)a.y,(f16)a.z,(f16)a.w,(f16)b.x,(f16)b.y,(f16)b.z,(f16)b.w};
      *(f16x8*)&W1f[wb] = o;
    }
  }
}

// ---------------- t2 = hidden @ W2^T + b1 + b2 ----------------
__global__ __launch_bounds__(256) void t2_kernel(
    const float* __restrict__ hidden, const float* __restrict__ W2,
    const float* __restrict__ b1, const float* __restrict__ b2,
    float* __restrict__ t2)
{
  const int gw   = blockIdx.x * 4 + (threadIdx.x >> 6);
  const int n    = gw >> 5;
  const int b    = gw & 31;
  const int lane = threadIdx.x & 63;
  float acc = 0.f;
#pragma unroll
  for (int q = 0; q < 4; ++q) {
    floatx4 hv = *(const floatx4*)&hidden[b * HH + q * 256 + lane * 4];
    floatx4 wv = *(const floatx4*)&W2[(size_t)n * HH + q * 256 + lane * 4];
    acc += hv.x * wv.x + hv.y * wv.y + hv.z * wv.z + hv.w * wv.w;
  }
#pragma unroll
  for (int off = 1; off < 64; off <<= 1) acc += __shfl_xor(acc, off);
  if (lane == 0) t2[b * HH + n] = acc + b1[n] + b2[n];
}

// ---------------- f16 MFMA GEMM + tanh + dot(v) ----------------
__global__ __launch_bounds__(256) void gemm_energy_f16(
    const f16* __restrict__ hsf, const f16* __restrict__ W1f,
    const float* __restrict__ t2, const float* __restrict__ v,
    float* __restrict__ epart)
{
  __shared__ __align__(16) f16 Asm[128 * 64];
  __shared__ __align__(16) f16 Bsm[128 * 64];

  const int tid  = threadIdx.x;
  const int lane = tid & 63;
  const int w    = tid >> 6;
  const int quad = lane >> 4;
  const int l15  = lane & 15;
  const int wr   = w >> 1, wc = w & 1;

  // XCD-aware swizzle: 8 nb-blocks of one m-tile land consecutively on one XCD
  const int l     = blockIdx.x;
  const int x     = l & 7;
  const int jj_   = l >> 3;
  const int nb    = jj_ & 7;
  const int mtile = (jj_ >> 3) * 8 + x;
  const int mB    = mtile * 128;
  const int nB    = nb * 128;

  floatx4 acc[4][4];
#pragma unroll
  for (int i = 0; i < 4; ++i)
#pragma unroll
    for (int j = 0; j < 4; ++j) acc[i][j] = (floatx4){0.f, 0.f, 0.f, 0.f};

  for (int kt = 0; kt < HH; kt += 64) {
#pragma unroll
    for (int q = 0; q < 4; ++q) {
      const int W   = w * 4 + q;                 // wave-instruction index 0..15
      const int r   = W * 8 + (lane >> 3);       // tile row this lane fetches
      const int cbl = (lane & 7) ^ (r & 7);      // logical 16B colblock (XOR swizzle)
      gload16(&Asm[W * 64 * 8], &hsf[(size_t)(mB + r) * HH + kt + cbl * 8]);
      gload16(&Bsm[W * 64 * 8], &W1f[(size_t)(nB + r) * HH + kt + cbl * 8]);
    }
    __syncthreads();
#pragma unroll
    for (int ks = 0; ks < 2; ++ks) {
      f16x8 af[4], bfr[4];
#pragma unroll
      for (int i = 0; i < 4; ++i) {
        const int r   = wr * 64 + i * 16 + l15;
        const int cbp = (ks * 4 + quad) ^ (r & 7);
        af[i] = *(const f16x8*)&Asm[(r * 8 + cbp) * 8];
      }
#pragma unroll
      for (int j = 0; j < 4; ++j) {
        const int r   = wc * 64 + j * 16 + l15;
        const int cbp = (ks * 4 + quad) ^ (r & 7);
        bfr[j] = *(const f16x8*)&Bsm[(r * 8 + cbp) * 8];
      }
#pragma unroll
      for (int i = 0; i < 4; ++i)
#pragma unroll
        for (int j = 0; j < 4; ++j)
          acc[i][j] = __builtin_amdgcn_mfma_f32_16x16x32_f16(af[i], bfr[j], acc[i][j], 0, 0, 0);
    }
    __syncthreads();
  }

  // epilogue: C/D layout col=lane&15, row=quad*4+reg.
  // write transposed: epart[p][b][s], p = nb*2+wc
  float vv[4];
#pragma unroll
  for (int j = 0; j < 4; ++j) vv[j] = v[nB + wc * 64 + j * 16 + l15];
#pragma unroll
  for (int i = 0; i < 4; ++i) {
#pragma unroll
    for (int reg = 0; reg < 4; ++reg) {
      const int m = mB + wr * 64 + i * 16 + quad * 4 + reg;
      const int b = m & (BB - 1);
      const int s = m >> 5;
      float rs = 0.f;
#pragma unroll
      for (int j = 0; j < 4; ++j) {
        const int n = nB + wc * 64 + j * 16 + l15;
        rs += tanh_fast(acc[i][j][reg] + t2[b * HH + n]) * vv[j];
      }
      rs += __shfl_xor(rs, 1);
      rs += __shfl_xor(rs, 2);
      rs += __shfl_xor(rs, 4);
      rs += __shfl_xor(rs, 8);
      if (l15 == 0) epart[(size_t)(nb * 2 + wc) * MM + b * SS + s] = rs;
    }
  }
}

// ---------------- softmax over s per batch column ----------------
// epart[p][b][s] -> coalesced in s. 32 blocks x 1024 threads, 2 s per thread.
// attn written as attn[b][s].
__global__ __launch_bounds__(1024) void softmax16t(
    const float* __restrict__ epart, const int* __restrict__ masks,
    float* __restrict__ attn)
{
  const int b = blockIdx.x;
  const int tid = threadIdx.x;   // 0..1023
  __shared__ float redm[16], reds[16];
  float em[2];
  float lmax = -3e38f;
#pragma unroll
  for (int it = 0; it < 2; ++it) {
    const int s = it * 1024 + tid;
    float e = 0.f;
#pragma unroll
    for (int p = 0; p < 16; ++p) e += epart[(size_t)p * MM + b * SS + s];
    if (masks[s * BB + b] == 0) e = -1e10f;
    em[it] = e;
    lmax = fmaxf(lmax, e);
  }
#pragma unroll
  for (int off = 1; off < 64; off <<= 1) lmax = fmaxf(lmax, __shfl_xor(lmax, off));
  if ((tid & 63) == 0) redm[tid >> 6] = lmax;
  __syncthreads();
#pragma unroll
  for (int i = 0; i < 16; ++i) lmax = fmaxf(lmax, redm[i]);
  float lsum = 0.f;
#pragma unroll
  for (int it = 0; it < 2; ++it) { em[it] = __expf(em[it] - lmax); lsum += em[it]; }
#pragma unroll
  for (int off = 1; off < 64; off <<= 1) lsum += __shfl_xor(lsum, off);
  if ((tid & 63) == 0) reds[tid >> 6] = lsum;
  __syncthreads();
  float tsum = 0.f;
#pragma unroll
  for (int i = 0; i < 16; ++i) tsum += reds[i];
  const float inv = 1.0f / tsum;
#pragma unroll
  for (int it = 0; it < 2; ++it) attn[b * SS + it * 1024 + tid] = em[it] * inv;
}

// ---------------- context partials from f16 hs ----------------
// attn[b][s] chunk preloaded to LDS -> no dependent global scalar load per s.
// 256 threads x f16x4 = exactly H=1024. Grid (b=32, sc=32), 64 s per block.
__global__ __launch_bounds__(256) void context_f16t(
    const f16* __restrict__ hsf, const float* __restrict__ attn,
    float* __restrict__ ctxp)
{
  const int b  = blockIdx.x;
  const int sc = blockIdx.y;
  const int tid = threadIdx.x;
  __shared__ float sat[64];
  if (tid < 64) sat[tid] = attn[b * SS + sc * 64 + tid];
  __syncthreads();
  floatx4 acc = {0.f, 0.f, 0.f, 0.f};
#pragma unroll 4
  for (int s = 0; s < 64; ++s) {
    const float a = sat[s];
    if (a != 0.f) {   // block-uniform branch; masked rows skip the load
      f16x4 h = *(const f16x4*)&hsf[(size_t)((sc * 64 + s) * BB + b) * HH + tid * 4];
      acc.x += a * (float)h[0];
      acc.y += a * (float)h[1];
      acc.z += a * (float)h[2];
      acc.w += a * (float)h[3];
    }
  }
  *(floatx4*)&ctxp[(size_t)(sc * BB + b) * HH + tid * 4] = acc;
}

__global__ __launch_bounds__(256) void ctx_reduce32(
    const float* __restrict__ ctxp, float* __restrict__ out)
{
  const int i = blockIdx.x * 256 + threadIdx.x;
  float s = 0.f;
#pragma unroll
  for (int sc = 0; sc < 32; ++sc) s += ctxp[(size_t)sc * (BB * HH) + i];
  out[i] = s;
}

// ================= fallback path (round-2, known-passing, 3.4 MB ws) =================
__global__ __launch_bounds__(256) void gemm_energy_fb(
    const float* __restrict__ hs, const float* __restrict__ W1,
    const float* __restrict__ t2, const float* __restrict__ v,
    float* __restrict__ epart)
{
  const int tid = threadIdx.x;
  const int nb  = blockIdx.x;
  const int mB  = blockIdx.y * 128;
  __shared__ __align__(16) f16 Asm[128][72];
  __shared__ __align__(16) f16 Bsm[128][72];
  const int lane = tid & 63;
  const int w    = tid >> 6;
  const int quad = lane >> 4;
  const int l15  = lane & 15;
  floatx4 acc[2][8];
#pragma unroll
  for (int i = 0; i < 2; ++i)
#pragma unroll
    for (int j = 0; j < 8; ++j) acc[i][j] = (floatx4){0.f, 0.f, 0.f, 0.f};
  const int srow = tid >> 4;
  const int scol = (tid & 15) * 4;
  const float* Abase = hs + (size_t)(mB + srow) * HH + scol;
  const float* Bbase = W1 + (size_t)(nb * 128 + srow) * HH + scol;
  for (int kt = 0; kt < HH; kt += 64) {
#pragma unroll
    for (int p = 0; p < 8; ++p) {
      floatx4 fa = *(const floatx4*)(Abase + (size_t)(p * 16) * HH + kt);
      floatx4 fb = *(const floatx4*)(Bbase + (size_t)(p * 16) * HH + kt);
      f16x4 ha = {(f16)fa.x, (f16)fa.y, (f16)fa.z, (f16)fa.w};
      f16x4 hb = {(f16)fb.x, (f16)fb.y, (f16)fb.z, (f16)fb.w};
      *(f16x4*)&Asm[p * 16 + srow][scol] = ha;
      *(f16x4*)&Bsm[p * 16 + srow][scol] = hb;
    }
    __syncthreads();
#pragma unroll
    for (int ks = 0; ks < 2; ++ks) {
      f16x8 af[2], bfr[8];
#pragma unroll
      for (int i = 0; i < 2; ++i)
        af[i] = *(const f16x8*)&Asm[w * 32 + i * 16 + l15][ks * 32 + quad * 8];
#pragma unroll
      for (int j = 0; j < 8; ++j)
        bfr[j] = *(const f16x8*)&Bsm[j * 16 + l15][ks * 32 + quad * 8];
#pragma unroll
      for (int i = 0; i < 2; ++i)
#pragma unroll
        for (int j = 0; j < 8; ++j)
          acc[i][j] = __builtin_amdgcn_mfma_f32_16x16x32_f16(af[i], bfr[j], acc[i][j], 0, 0, 0);
    }
    __syncthreads();
  }
  const int nB = nb * 128;
#pragma unroll
  for (int i = 0; i < 2; ++i) {
#pragma unroll
    for (int reg = 0; reg < 4; ++reg) {
      const int m = mB + w * 32 + i * 16 + quad * 4 + reg;
      const int b = m & (BB - 1);
      float rs = 0.f;
#pragma unroll
      for (int j = 0; j < 8; ++j) {
        const int n = nB + j * 16 + l15;
        rs += tanh_fast(acc[i][j][reg] + t2[b * HH + n]) * v[n];
      }
      rs += __shfl_xor(rs, 1);
      rs += __shfl_xor(rs, 2);
      rs += __shfl_xor(rs, 4);
      rs += __shfl_xor(rs, 8);
      if (l15 == 0) epart[(size_t)nb * MM + m] = rs;
    }
  }
}

__global__ __launch_bounds__(256) void softmax8(
    const float* __restrict__ epart, const int* __restrict__ masks,
    float* __restrict__ attn)
{
  const int b = blockIdx.x;
  const int tid = threadIdx.x;
  __shared__ float redm[4], reds[4];
  float em[8];
  float lmax = -3e38f;
#pragma unroll
  for (int it = 0; it < 8; ++it) {
    const int s = it * 256 + tid;
    float e = 0.f;
#pragma unroll
    for (int p = 0; p < 8; ++p) e += epart[(size_t)p * MM + s * BB + b];
    if (masks[s * BB + b] == 0) e = -1e10f;
    em[it] = e;
    lmax = fmaxf(lmax, e);
  }
#pragma unroll
  for (int off = 1; off < 64; off <<= 1) lmax = fmaxf(lmax, __shfl_xor(lmax, off));
  if ((tid & 63) == 0) redm[tid >> 6] = lmax;
  __syncthreads();
  lmax = fmaxf(fmaxf(redm[0], redm[1]), fmaxf(redm[2], redm[3]));
  float lsum = 0.f;
#pragma unroll
  for (int it = 0; it < 8; ++it) { em[it] = __expf(em[it] - lmax); lsum += em[it]; }
#pragma unroll
  for (int off = 1; off < 64; off <<= 1) lsum += __shfl_xor(lsum, off);
  if ((tid & 63) == 0) reds[tid >> 6] = lsum;
  __syncthreads();
  const float inv = 1.0f / (reds[0] + reds[1] + reds[2] + reds[3]);
#pragma unroll
  for (int it = 0; it < 8; ++it) attn[(it * 256 + tid) * BB + b] = em[it] * inv;
}

__global__ __launch_bounds__(256) void context_fb(
    const float* __restrict__ hs, const float* __restrict__ attn,
    float* __restrict__ ctxp)
{
  const int b  = blockIdx.x;
  const int sc = blockIdx.y;
  const int tid = threadIdx.x;
  floatx4 acc = {0.f, 0.f, 0.f, 0.f};
  for (int s = sc * 256; s < sc * 256 + 256; ++s) {
    const float a = attn[s * BB + b];
    if (a != 0.f) {
      floatx4 h = *(const floatx4*)&hs[(size_t)(s * BB + b) * HH + tid * 4];
      acc.x += a * h.x; acc.y += a * h.y; acc.z += a * h.z; acc.w += a * h.w;
    }
  }
  *(floatx4*)&ctxp[(size_t)(sc * BB + b) * HH + tid * 4] = acc;
}

__global__ __launch_bounds__(256) void ctx_reduce8(
    const float* __restrict__ ctxp, float* __restrict__ out)
{
  const int i = blockIdx.x * 256 + threadIdx.x;
  float s = 0.f;
#pragma unroll
  for (int sc = 0; sc < 8; ++sc) s += ctxp[(size_t)sc * (BB * HH) + i];
  out[i] = s;
}

extern "C" void kernel_launch(void* const* d_in, const int* in_sizes, int n_in,
                              void* d_out, int out_size, void* d_ws, size_t ws_size,
                              hipStream_t stream) {
  const float* hidden = (const float*)d_in[0];  // (1,B,H)
  const float* hs     = (const float*)d_in[1];  // (S,B,H)
  const int*   masks  = (const int*)d_in[2];    // (S,B)
  const float* W1     = (const float*)d_in[3];  // (H,H)
  const float* b1     = (const float*)d_in[4];  // (H,)
  const float* W2     = (const float*)d_in[5];  // (H,H)
  const float* b2     = (const float*)d_in[6];  // (H,)
  const float* v      = (const float*)d_in[7];  // (H,)
  float* out = (float*)d_out;                   // (1,B,H)

  const size_t hsf_b   = (size_t)MM * HH * 2;    // 128 MB
  const size_t w1f_b   = (size_t)HH * HH * 2;    // 2 MB
  const size_t epart_b = (size_t)16 * MM * 4;    // 4 MB
  const size_t attn_b  = (size_t)MM * 4;         // 256 KB
  const size_t t2_b    = (size_t)BB * HH * 4;    // 128 KB
  const size_t ctxp_b  = (size_t)32 * BB * HH * 4; // 4 MB
  const size_t need = hsf_b + w1f_b + epart_b + attn_b + t2_b + ctxp_b;

  if (ws_size >= need) {
    char* p = (char*)d_ws;
    f16*   hsf   = (f16*)p;              p += hsf_b;
    f16*   W1f   = (f16*)p;              p += w1f_b;
    float* epart = (float*)p;            p += epart_b;
    float* attn  = (float*)p;            p += attn_b;
    float* t2    = (float*)p;            p += t2_b;
    float* ctxp  = (float*)p;

    convert_f16<<<dim3(33280), 256, 0, stream>>>(hs, W1, hsf, W1f);
    t2_kernel<<<dim3(BB * HH / 4), 256, 0, stream>>>(hidden, W2, b1, b2, t2);
    gemm_energy_f16<<<dim3(4096), 256, 0, stream>>>(hsf, W1f, t2, v, epart);
    softmax16t<<<dim3(BB), 1024, 0, stream>>>(epart, masks, attn);
    context_f16t<<<dim3(BB, 32), 256, 0, stream>>>(hsf, attn, ctxp);
    ctx_reduce32<<<dim3(BB * HH / 256), 256, 0, stream>>>(ctxp, out);
  } else {
    float* epart = (float*)d_ws;          // 8*MM
    float* attn  = epart + 8 * MM;        // MM
    float* t2    = attn + MM;             // BB*HH
    float* ctxp  = t2 + BB * HH;          // 8*BB*HH

    t2_kernel<<<dim3(BB * HH / 4), 256, 0, stream>>>(hidden, W2, b1, b2, t2);
    gemm_energy_fb<<<dim3(8, MM / 128), 256, 0, stream>>>(hs, W1, t2, v, epart);
    softmax8<<<dim3(BB), 256, 0, stream>>>(epart, masks, attn);
    context_fb<<<dim3(BB, 8), 256, 0, stream>>>(hs, attn, ctxp);
    ctx_reduce8<<<dim3(BB * HH / 256), 256, 0, stream>>>(ctxp, out);
  }
}